// Round 11
// baseline (144.152 us; speedup 1.0000x reference)
//
#include <hip/hip_runtime.h>

// KLD RepPoints loss, R10: R2 structure + nontemporal (nt) loads.
// R2..R9: nine structural variants (request width/count, line-visits,
// batch depth 1/2/4, explicit pipeline, sched_barrier-pinned, LDS staging
// with copy-identical dense loads) ALL land at ~33-37us = ~3.1 TB/s read.
// Invariance to instruction shape + sensitivity only to write-path
// pathologies => system-level read-path ceiling (inputs are L2/L3-dirty
// from the harness restore; FETCH_SIZE=53MB of 104MB confirms). Last
// memory-system knob: nt loads (read-once stream, no-allocate policy).

typedef float v2f __attribute__((ext_vector_type(2)));

__global__ __launch_bounds__(256) void kld_partial_kernel(
    const float* __restrict__ pred,    // [n][9][2]
    const float* __restrict__ target,  // [n][4][2]
    float* __restrict__ ws,            // [gridDim.x] partial sums
    int n_total)
{
    int n = blockIdx.x * blockDim.x + threadIdx.x;
    float loss = 0.0f;
    if (n < n_total) {
        // ---- pred moments (nt float2 loads, stride 72B) ----
        const v2f* p = reinterpret_cast<const v2f*>(pred + (size_t)n * 18);
        v2f v0 = __builtin_nontemporal_load(p + 0);
        v2f v1 = __builtin_nontemporal_load(p + 1);
        v2f v2 = __builtin_nontemporal_load(p + 2);
        v2f v3 = __builtin_nontemporal_load(p + 3);
        v2f v4 = __builtin_nontemporal_load(p + 4);
        v2f v5 = __builtin_nontemporal_load(p + 5);
        v2f v6 = __builtin_nontemporal_load(p + 6);
        v2f v7 = __builtin_nontemporal_load(p + 7);
        v2f v8 = __builtin_nontemporal_load(p + 8);

        const v2f* t = reinterpret_cast<const v2f*>(target + (size_t)n * 8);
        v2f q0 = __builtin_nontemporal_load(t + 0);
        v2f q1 = __builtin_nontemporal_load(t + 1);
        v2f q2 = __builtin_nontemporal_load(t + 2);
        v2f q3 = __builtin_nontemporal_load(t + 3);

        const float inv9 = 1.0f / 9.0f;
        float sx = v0.x + v1.x + v2.x + v3.x + v4.x + v5.x + v6.x + v7.x + v8.x;
        float sy = v0.y + v1.y + v2.y + v3.y + v4.y + v5.y + v6.y + v7.y + v8.y;
        float mux = sx * inv9, muy = sy * inv9;

        float a, b, d, ux, uy;
        ux = v0.x - mux; uy = v0.y - muy; a  = ux * ux; b  = ux * uy; d  = uy * uy;
        ux = v1.x - mux; uy = v1.y - muy; a += ux * ux; b += ux * uy; d += uy * uy;
        ux = v2.x - mux; uy = v2.y - muy; a += ux * ux; b += ux * uy; d += uy * uy;
        ux = v3.x - mux; uy = v3.y - muy; a += ux * ux; b += ux * uy; d += uy * uy;
        ux = v4.x - mux; uy = v4.y - muy; a += ux * ux; b += ux * uy; d += uy * uy;
        ux = v5.x - mux; uy = v5.y - muy; a += ux * ux; b += ux * uy; d += uy * uy;
        ux = v6.x - mux; uy = v6.y - muy; a += ux * ux; b += ux * uy; d += uy * uy;
        ux = v7.x - mux; uy = v7.y - muy; a += ux * ux; b += ux * uy; d += uy * uy;
        ux = v8.x - mux; uy = v8.y - muy; a += ux * ux; b += ux * uy; d += uy * uy;
        a = a * inv9 + 1e-6f;
        b = b * inv9;
        d = d * inv9 + 1e-6f;

        // ---- target box -> rotated Gaussian ----
        float tmux = (q0.x + q1.x + q2.x + q3.x) * 0.25f;
        float tmuy = (q0.y + q1.y + q2.y + q3.y) * 0.25f;
        float e1x = q1.x - q0.x, e1y = q1.y - q0.y;
        float e2x = q2.x - q1.x, e2y = q2.y - q1.y;
        float w = e1x * e1x + e1y * e1y;
        float h = e2x * e2x + e2y * e2y;
        float sw = sqrtf(w);
        float c = e1x / sw, s = e1y / sw;
        const float invLL = 1.0f / 36.0f;      // 1/(4*L*L), L=3
        float dw = w * invLL, dh = h * invLL;
        float tv00 = c * c * dw + s * s * dh;  // t_var = R diag(dw,dh) R^T
        float tv01 = c * s * (dw - dh);
        float tv11 = s * s * dw + c * c * dh;

        float t_det = tv00 * tv11 - tv01 * tv01;
        float p_det = a * d - b * b;
        float inv_tdet = 1.0f / t_det;

        float dx = mux - tmux, dy = muy - tmuy;
        float term1 = (dx * dx * tv11 - 2.0f * dx * dy * tv01 + dy * dy * tv00) * inv_tdet;
        float trace = (tv11 * a - 2.0f * tv01 * b + tv00 * d) * inv_tdet;
        float term2 = trace + logf(t_det / p_det);
        float kld = 0.5f * (term1 + term2) - 1.0f;
        float kl = fmaxf(kld, 1e-6f);
        loss = 1.0f - 1.0f / (2.0f + sqrtf(kl));
    }

    // ---- reduction: wave64 shuffle -> LDS -> one plain store per block ----
    #pragma unroll
    for (int off = 32; off > 0; off >>= 1)
        loss += __shfl_down(loss, off, 64);

    __shared__ float sm[4];
    int lane = threadIdx.x & 63;
    int wid  = threadIdx.x >> 6;
    if (lane == 0) sm[wid] = loss;
    __syncthreads();
    if (threadIdx.x == 0)
        ws[blockIdx.x] = sm[0] + sm[1] + sm[2] + sm[3];
}

__global__ __launch_bounds__(256) void kld_final_kernel(
    const float* __restrict__ ws, float* __restrict__ out,
    int nblocks, float inv_n)
{
    float s = 0.0f;
    for (int i = threadIdx.x; i < nblocks; i += 256)
        s += ws[i];

    #pragma unroll
    for (int off = 32; off > 0; off >>= 1)
        s += __shfl_down(s, off, 64);

    __shared__ float sm[4];
    int lane = threadIdx.x & 63;
    int wid  = threadIdx.x >> 6;
    if (lane == 0) sm[wid] = s;
    __syncthreads();
    if (threadIdx.x == 0)
        out[0] = (sm[0] + sm[1] + sm[2] + sm[3]) * inv_n;
}

extern "C" void kernel_launch(void* const* d_in, const int* in_sizes, int n_in,
                              void* d_out, int out_size, void* d_ws, size_t ws_size,
                              hipStream_t stream) {
    const float* pred   = (const float*)d_in[0];
    const float* target = (const float*)d_in[1];
    float* out = (float*)d_out;
    float* ws  = (float*)d_ws;

    int n = in_sizes[0] / 18;   // N elements (pred is N*9*2 floats)
    int nblocks = (n + 255) / 256;
    if (nblocks < 1) nblocks = 1;

    kld_partial_kernel<<<nblocks, 256, 0, stream>>>(pred, target, ws, n);
    kld_final_kernel<<<1, 256, 0, stream>>>(ws, out, nblocks, 1.0f / (float)n);
}